// Round 6
// baseline (3125.644 us; speedup 1.0000x reference)
//
#include <hip/hip_runtime.h>
#include <hip/hip_bf16.h>
#include <stdint.h>

#define B_ 8
#define L_ 1024
#define H_ 768
#define E_ 16
#define W_ 504
#define DFF_ 512
#define N_ 5982
#define NE_ (N_*E_)    // 95712 candidates per batch
#define BNE_ (B_*NE_)  // 765696

typedef unsigned long long u64;
typedef unsigned int u32;
typedef __hip_bfloat16 bf16;

// runtime-dtype loader: flag==1 -> fp32 buffer, flag==0 -> bf16 buffer
__device__ __forceinline__ float ldin(const void* p, size_t i, int f32){
    if (f32) return ((const float*)p)[i];
    return __bfloat162float(((const bf16*)p)[i]);
}

// ---------------- dtype probe ----------------
__global__ void k_probe(const void* hs, int* flag){
    int tid = threadIdx.x;
    const unsigned short* u = (const unsigned short*)hs;
    int weird = 0;
    for (int i = tid; i < 16384; i += 256){
        u32 f = ((u32)u[i]) << 16;
        u32 ex = (f >> 23) & 0xFF;
        if (ex >= 137) weird++;   // |x| >= 1024, inf, nan
    }
    __shared__ int red[256];
    red[tid] = weird; __syncthreads();
    for (int s = 128; s > 0; s >>= 1){ if (tid < s) red[tid] += red[tid+s]; __syncthreads(); }
    if (tid == 0) flag[0] = (red[0] > 64) ? 1 : 0;   // 1 = inputs are fp32
}

// ---------------- span tables: literal reference double loop ----------------
__global__ void k_tables(int* starts, int* ends){
    if (threadIdx.x != 0 || blockIdx.x != 0) return;
    int idx = 0;
    for (int s = 0; s < W_; s++)
        for (int e = s; e < min(W_, s + 12); e++){ starts[idx] = s; ends[idx] = e; idx++; }
}

// ---------------- token lists per (b,w): serial, deterministic ----------------
__global__ void k_toklist(const int* __restrict__ text_mask, const int* __restrict__ word_index,
                          int* __restrict__ tok, int* __restrict__ tokc){
    int b = blockIdx.x;
    if (threadIdx.x != 0) return;
    for (int w = 0; w < W_; w++) tokc[b*W_ + w] = 0;
    for (int l = 0; l < L_; l++){
        int w = word_index[b*L_ + l];
        if (text_mask[b*L_ + l] == 1 && w >= 0 && w < W_){
            int c = tokc[b*W_ + w];
            if (c < 4) tok[(b*W_ + w)*4 + c] = l;
            tokc[b*W_ + w] = c + 1;
        }
    }
}

// ---------------- word mean pooling (gather, no atomics) ----------------
__global__ void k_pool(const void* __restrict__ hs, const int* __restrict__ flag,
                       const int* __restrict__ tok, const int* __restrict__ tokc,
                       float* __restrict__ wemb){
    int idx = blockIdx.x*256 + threadIdx.x;      // over B*W*H
    if (idx >= B_*W_*H_) return;
    int f32 = flag[0];
    int h = idx % H_; int bw = idx / H_; int b = bw / W_;
    int c = tokc[bw]; int cc = min(c, 4);
    double s = 0.0;
    for (int k = 0; k < cc; k++){
        int l = tok[bw*4 + k];
        s += (double)ldin(hs, ((size_t)(b*L_ + l))*H_ + h, f32);
    }
    float denom = (float)max(c, 1);
    wemb[idx] = (float)(s / (double)denom);
}

// ---------------- entity positions: literal stable scan ----------------
__global__ void k_entpos(const int* __restrict__ ent_mask, int* __restrict__ ent_pos){
    int b = blockIdx.x;
    if (threadIdx.x != 0) return;
    int c = 0;
    for (int l = 0; l < L_ && c < E_; l++) if (ent_mask[b*L_ + l] == 1) ent_pos[b*E_ + c++] = l;
    for (int l = 0; l < L_ && c < E_; l++) if (ent_mask[b*L_ + l] != 1) ent_pos[b*E_ + c++] = l;
}

// ---------------- entity MLP (fp64 accumulate) ----------------
__global__ void k_ent_mlp(const void* __restrict__ hs, const int* __restrict__ flag,
                          const int* __restrict__ ent_pos,
                          const void* __restrict__ w1, const void* __restrict__ b1,
                          const void* __restrict__ w2, const void* __restrict__ b2,
                          float* __restrict__ ent_vec){
    __shared__ float x[H_];
    __shared__ float hid[DFF_];
    int be = blockIdx.x; int b = be / E_;
    int tid = threadIdx.x;
    int f32 = flag[0];
    int pos = ent_pos[be];
    size_t xbase = ((size_t)b*L_ + pos)*H_;
    for (int j = tid; j < H_; j += 256) x[j] = ldin(hs, xbase + j, f32);
    __syncthreads();
    for (int d = tid; d < DFF_; d += 256){
        double acc = (double)ldin(b1, d, f32);
        for (int h = 0; h < H_; h++) acc += (double)x[h]*(double)ldin(w1, (size_t)h*DFF_ + d, f32);
        hid[d] = (float)(acc > 0.0 ? acc : 0.01*acc);
    }
    __syncthreads();
    for (int j = tid; j < H_; j += 256){
        double acc = (double)ldin(b2, j, f32);
        for (int d = 0; d < DFF_; d++) acc += (double)hid[d]*(double)ldin(w2, (size_t)d*H_ + j, f32);
        ent_vec[(size_t)be*H_ + j] = (float)acc;
    }
}

// ---------------- M[b] = span_w2 @ ent_vec[b]^T  (exact fold of 2nd linear) ----------------
__global__ void k_M(const void* __restrict__ span_w2, const int* __restrict__ flag,
                    const float* __restrict__ ent_vec, float* __restrict__ M){
    int blk = blockIdx.x; int b = blk/32; int dbase = (blk%32)*16;
    int tid = threadIdx.x; int d = dbase + (tid>>4); int e = tid&15;
    int f32 = flag[0];
    const float* ev = ent_vec + ((size_t)b*E_ + e)*H_;
    double acc = 0.0;
    for (int h = 0; h < H_; h++) acc += (double)ldin(span_w2, (size_t)d*H_ + h, f32)*(double)ev[h];
    M[((size_t)b*DFF_ + d)*E_ + e] = (float)acc;
}

__global__ void k_c(const void* __restrict__ span_b2, const int* __restrict__ flag,
                    const float* __restrict__ ent_vec, float* __restrict__ cvec){
    int i = blockIdx.x*blockDim.x + threadIdx.x;
    if (i >= B_*E_) return;
    int f32 = flag[0];
    const float* ev = ent_vec + (size_t)i*H_;
    double acc = 0.0;
    for (int h = 0; h < H_; h++) acc += (double)ldin(span_b2, h, f32)*(double)ev[h];
    cvec[i] = (float)acc;
}

// ---------------- P/Q projection, one batch per pass, one thread per output ----------------
__global__ void k_pq(const float* __restrict__ wemb, const void* __restrict__ w1,
                     const int* __restrict__ flag, float* __restrict__ PQ, int b){
    int idx = blockIdx.x*256 + threadIdx.x;      // over W_*1024
    if (idx >= W_*1024) return;
    int f32 = flag[0];
    int col = idx & 1023; int row = idx >> 10;
    const float* a = wemb + ((size_t)(b*W_ + row))*H_;
    size_t bofs = (col < DFF_) ? (size_t)col : ((size_t)H_*DFF_ + (col - DFF_));
    double acc = 0.0;
    for (int k = 0; k < H_; k++) acc += (double)a[k]*(double)ldin(w1, bofs + (size_t)k*DFF_, f32);
    PQ[(size_t)row*1024 + col] = (float)acc;
}

// ---------------- logits: one block (64 thr) per span ----------------
__global__ void k_logits(const float* __restrict__ PQ, const float* __restrict__ Mmat,
                         const float* __restrict__ cvec, const void* __restrict__ span_b1,
                         const int* __restrict__ flag,
                         const int* __restrict__ starts, const int* __restrict__ ends,
                         float* __restrict__ logits, float* __restrict__ outL, int b){
    __shared__ float hid[DFF_];
    __shared__ double red[64];
    int n = blockIdx.x; int tid = threadIdx.x;   // 64 threads
    int f32 = flag[0];
    int s = starts[n], e = ends[n];
    const float* P = PQ + (size_t)s*1024;
    const float* Q = PQ + (size_t)e*1024 + DFF_;
    for (int d = tid; d < DFF_; d += 64){
        float h = P[d] + Q[d] + ldin(span_b1, d, f32);
        hid[d] = h > 0.f ? h : 0.01f*h;
    }
    __syncthreads();
    int ee = tid & 15; int g = tid >> 4;         // 4 groups of 128
    const float* M = Mmat + (size_t)b*DFF_*E_;
    double acc = 0.0;
    for (int d = g*128; d < g*128 + 128; d++) acc += (double)hid[d]*(double)M[(size_t)d*E_ + ee];
    red[tid] = acc; __syncthreads();
    if (tid < E_){
        double t = red[tid] + red[16+tid] + red[32+tid] + red[48+tid];
        float lg = (float)(t + (double)cvec[b*E_ + tid]);
        size_t oi = ((size_t)b*N_ + n)*E_ + tid;
        logits[oi] = lg;
        outL[oi] = lg;                            // fp32 output
    }
}

// ---------------- ordered compaction of prob>0.5 candidates ----------------
__global__ void k_compact(const float* __restrict__ logits, u64* __restrict__ cand,
                          int* __restrict__ cnt){
    __shared__ u32 wt[16];
    __shared__ u32 wpre[17];
    __shared__ u32 sbase;
    int b = blockIdx.x; int tid = threadIdx.x;
    int lane = tid&63, wave = tid>>6;
    if (tid == 0) sbase = 0;
    __syncthreads();
    for (int base = 0; base < NE_; base += 1024){
        int c = base + tid;
        float lg = (c < NE_) ? logits[(size_t)b*NE_ + c] : -40.0f;
        float prob = 1.0f/(1.0f + expf(-lg));    // fp32 sigmoid = reference tie-classes
        bool f = prob > 0.5f;
        u64 bal = __ballot(f);
        if (lane == 0) wt[wave] = (u32)__popcll(bal);
        __syncthreads();
        if (tid == 0){ u32 r = 0; for (int w = 0; w < 16; w++){ wpre[w] = r; r += wt[w]; } wpre[16] = r; }
        __syncthreads();
        if (f){
            u32 rank = (u32)__popcll(bal & ((1ull<<lane) - 1ull));
            u32 pos = sbase + wpre[wave] + rank;
            u32 key = ~__float_as_uint(prob);    // ascending key == descending prob
            cand[(size_t)b*NE_ + pos] = ((u64)key<<32) | (u64)(u32)c;
        }
        __syncthreads();
        if (tid == 0) sbase += wpre[16];
        __syncthreads();
    }
    if (tid == 0) cnt[b] = (int)sbase;
}

// ---------------- stable LSD radix sort, 4-bit digits on key bits [32..63] ----------------
__global__ void k_radix(const u64* __restrict__ in, u64* __restrict__ out,
                        const int* __restrict__ cnt, int shift){
    __shared__ u32 hist[16*512];
    __shared__ u32 wtot[8];
    __shared__ u32 woff[8];
    int b = blockIdx.x; int t = threadIdx.x;
    int n = cnt[b];
    const u64* ip = in + (size_t)b*NE_;
    u64* op = out + (size_t)b*NE_;
    for (int j = t; j < 16*512; j += 512) hist[j] = 0;
    __syncthreads();
    int chunk = (n + 511) >> 9;
    int lo = t*chunk; int hi = lo + chunk; if (hi > n) hi = n; if (lo > n) lo = n;
    for (int i = lo; i < hi; i++){
        int d = (int)((ip[i] >> shift) & 15ull);
        hist[d*512 + t]++;
    }
    __syncthreads();
    u32 v[16];
    #pragma unroll
    for (int j = 0; j < 16; j++) v[j] = hist[t*16 + j];
    u32 run = 0;
    #pragma unroll
    for (int j = 0; j < 16; j++){ u32 tmp = v[j]; v[j] = run; run += tmp; }
    int lane = t&63, wave = t>>6;
    u32 inc = run;
    for (int dstep = 1; dstep < 64; dstep <<= 1){
        u32 o = __shfl_up(inc, dstep, 64);
        if (lane >= dstep) inc += o;
    }
    u32 excl = inc - run;
    if (lane == 63) wtot[wave] = inc;
    __syncthreads();
    if (t == 0){ u32 r = 0; for (int w = 0; w < 8; w++){ woff[w] = r; r += wtot[w]; } }
    __syncthreads();
    u32 gbase = woff[wave] + excl;
    #pragma unroll
    for (int j = 0; j < 16; j++) hist[t*16 + j] = gbase + v[j];
    __syncthreads();
    for (int i = lo; i < hi; i++){
        u64 val = ip[i];
        int d = (int)((val >> shift) & 15ull);
        u32 p = hist[d*512 + t];
        hist[d*512 + t] = p + 1;
        op[p] = val;
    }
}

// ---------------- greedy NMS decode ----------------
__global__ void k_decode(const u64* __restrict__ sorted, const int* __restrict__ cnt,
                         const int* __restrict__ starts, const int* __restrict__ ends,
                         float* __restrict__ outSel){
    __shared__ u64 covsh[8];
    int b = blockIdx.x; int lane = threadIdx.x;
    if (lane < 8) covsh[lane] = 0ull;
    __syncthreads();
    int n = cnt[b];
    const u64* sp = sorted + (size_t)b*NE_;
    int covcnt = 0;
    for (int base = 0; base < n; base += 64){
        int i = base + lane;
        bool has = i < n;
        u64 v = has ? sp[i] : 0ull;
        int c = (int)(v & 0xffffffffull);
        int nidx = c >> 4;
        int s = 0, e = -1;
        if (has){ s = starts[nidx]; e = ends[nidx]; }
        int w0 = s>>6; int sh0 = s&63; int len = e - s + 1;
        u64 m0 = has ? ((((len>=64)?~0ull:((1ull<<len)-1ull)))<<sh0) : 0ull;
        u64 m1 = (has && sh0+len > 64) ? (((1ull<<len)-1ull)>>(64-sh0)) : 0ull;
        int w1 = (w0+1 < 8) ? w0+1 : 7;
        bool tent = has && ((covsh[w0]&m0)==0ull) && ((covsh[w1]&m1)==0ull);
        u64 bal = __ballot(tent);
        while (bal){
            int j = __builtin_ctzll(bal);
            int js = __shfl(s, j); int je = __shfl(e, j); int jc = __shfl(c, j);
            int jw0 = js>>6, jsh = js&63, jlen = je - js + 1;
            u64 jm0 = (((jlen>=64)?~0ull:((1ull<<jlen)-1ull)))<<jsh;
            u64 jm1 = (jsh+jlen > 64) ? (((1ull<<jlen)-1ull)>>(64-jsh)) : 0ull;
            int jw1 = (jw0+1 < 8) ? jw0+1 : 7;
            u64 o0 = covsh[jw0], o1 = covsh[jw1];
            covcnt += (int)(__popcll(jm0 & ~o0) + ((jw1 != jw0) ? __popcll(jm1 & ~o1) : 0));
            if (lane == 0){
                covsh[jw0] = o0 | jm0;
                if (jw1 != jw0) covsh[jw1] = o1 | jm1;
                outSel[(size_t)BNE_ + (size_t)b*NE_ + (size_t)jc] = 1.0f;   // fp32 output
            }
            __syncthreads();
            tent = tent && (lane > j) && ((covsh[w0]&m0)==0ull) && ((covsh[w1]&m1)==0ull);
            bal = __ballot(tent);
        }
        if (covcnt >= W_) break;
    }
}

extern "C" void kernel_launch(void* const* d_in, const int* in_sizes, int n_in,
                              void* d_out, int out_size, void* d_ws, size_t ws_size,
                              hipStream_t stream){
    const void* hs        = d_in[0];
    const void* ent_w1    = d_in[1];
    const void* ent_b1    = d_in[2];
    const void* ent_w2    = d_in[3];
    const void* ent_b2    = d_in[4];
    const void* span_w1   = d_in[5];
    const void* span_b1   = d_in[6];
    const void* span_w2   = d_in[7];
    const void* span_b2   = d_in[8];
    const int*  text_mask = (const int*)d_in[9];
    const int*  ent_mask  = (const int*)d_in[10];
    const int*  word_index= (const int*)d_in[11];
    float* out = (float*)d_out;                   // fp32 outputs (logits fp32, selected bool->fp32)

    // ---- workspace layout (peak ~18.3 MB; wemb region reused for sort buffers) ----
    char* wsbase = (char*)d_ws; size_t off = 0;
    auto alloc = [&](size_t bytes)->void*{ void* p = wsbase + off; off = (off + bytes + 255) & ~(size_t)255; return p; };
    char*  region1 = (char*)alloc((size_t)B_*W_*H_*4);   // 12,386,304 B
    float* wemb   = (float*)region1;                      // phase 1
    u64*   candA  = (u64*)region1;                        // phase 2 (6,125,568 B)
    u64*   candB  = (u64*)(region1 + (size_t)BNE_*8);     // phase 2 (+6,125,568 <= region1)
    int*   tok    = (int*)  alloc((size_t)B_*W_*4*4);
    int*   tokc   = (int*)  alloc((size_t)B_*W_*4);
    float* PQ     = (float*)alloc((size_t)W_*1024*4);     // 2,064,384 B (1 batch per pass)
    float* logits = (float*)alloc((size_t)BNE_*4);        // 3,062,784 B
    int*   entpos = (int*)  alloc((size_t)B_*E_*4);
    float* entvec = (float*)alloc((size_t)B_*E_*H_*4);
    float* Mmat   = (float*)alloc((size_t)B_*DFF_*E_*4);
    float* cvec   = (float*)alloc((size_t)B_*E_*4);
    int*   starts = (int*)  alloc((size_t)N_*4);
    int*   ends   = (int*)  alloc((size_t)N_*4);
    int*   cntp   = (int*)  alloc((size_t)B_*4);
    int*   flag   = (int*)  alloc(256);

    hipMemsetAsync((void*)(out + BNE_), 0, (size_t)BNE_*4, stream);  // selected := 0.0f

    k_probe<<<1,256,0,stream>>>(hs, flag);
    k_tables<<<1,64,0,stream>>>(starts, ends);
    k_toklist<<<B_,64,0,stream>>>(text_mask, word_index, tok, tokc);
    k_pool<<<(B_*W_*H_+255)/256,256,0,stream>>>(hs, flag, tok, tokc, wemb);
    k_entpos<<<B_,64,0,stream>>>(ent_mask, entpos);
    k_ent_mlp<<<B_*E_,256,0,stream>>>(hs, flag, entpos, ent_w1, ent_b1, ent_w2, ent_b2, entvec);
    k_M<<<B_*32,256,0,stream>>>(span_w2, flag, entvec, Mmat);
    k_c<<<(B_*E_+63)/64,64,0,stream>>>(span_b2, flag, entvec, cvec);
    for (int b = 0; b < B_; b++){
        k_pq<<<(W_*1024+255)/256,256,0,stream>>>(wemb, span_w1, flag, PQ, b);
        k_logits<<<N_,64,0,stream>>>(PQ, Mmat, cvec, span_b1, flag, starts, ends, logits, out, b);
    }
    // wemb dead from here; region1 becomes candA/candB
    k_compact<<<B_,1024,0,stream>>>(logits, candA, cntp);
    for (int p = 0; p < 8; p++){
        const u64* ip = (p&1) ? candB : candA;
        u64*       op = (p&1) ? candA : candB;
        k_radix<<<B_,512,0,stream>>>(ip, op, cntp, 32 + 4*p);
    }
    k_decode<<<B_,64,0,stream>>>(candA, cntp, starts, ends, out);
}

// Round 7
// 1404.263 us; speedup vs baseline: 2.2258x; 2.2258x over previous
//
#include <hip/hip_runtime.h>
#include <hip/hip_bf16.h>
#include <stdint.h>

#define B_ 8
#define L_ 1024
#define H_ 768
#define E_ 16
#define W_ 504
#define DFF_ 512
#define N_ 5982
#define NE_ (N_*E_)    // 95712 candidates per batch
#define BNE_ (B_*NE_)  // 765696
#define MAXC_ 6144     // padded per-batch candidate capacity (>= N_)

typedef unsigned long long u64;
typedef unsigned int u32;

// ---------------- span tables (closed-form rowstart, verified vs serial reference) ----------------
__global__ void k_tables(int* starts, int* ends){
    int s = blockIdx.x*64 + threadIdx.x;
    if (s >= W_) return;
    int s0 = W_ - 11;  // 493
    int t = s - s0;
    int rs = (s <= s0) ? 12*s : (12*s0 + t*11 - (t*(t-1))/2);
    int cnt = min(12, W_ - s);
    for (int i = 0; i < cnt; i++){ starts[rs+i] = s; ends[rs+i] = s+i; }
}

// ---------------- token lists: parallel build + deterministic sort ----------------
__global__ void k_toklist(const int* __restrict__ tm, const int* __restrict__ wi,
                          int* __restrict__ tok, int* __restrict__ tokc){
    int i = blockIdx.x*256 + threadIdx.x;
    if (i >= B_*L_) return;
    int w = wi[i];
    if (tm[i] == 1 && w >= 0 && w < W_){
        int b = i / L_;
        int bw = b*W_ + w;
        int pos = atomicAdd(&tokc[bw], 1);
        if (pos < 4) tok[bw*4 + pos] = i - b*L_;
    }
}

__global__ void k_toksort(int* __restrict__ tok, const int* __restrict__ tokc){
    int bw = blockIdx.x*256 + threadIdx.x;
    if (bw >= B_*W_) return;
    int c = min(tokc[bw], 4);
    int v[4];
    for (int k = 0; k < c; k++) v[k] = tok[bw*4 + k];
    for (int a = 1; a < c; a++){ int x = v[a]; int j = a-1; while (j >= 0 && v[j] > x){ v[j+1] = v[j]; j--; } v[j+1] = x; }
    for (int k = 0; k < c; k++) tok[bw*4 + k] = v[k];
}

// ---------------- word mean pooling (gather, deterministic) ----------------
__global__ void k_pool(const float* __restrict__ hs,
                       const int* __restrict__ tok, const int* __restrict__ tokc,
                       float* __restrict__ wemb){
    int idx = blockIdx.x*256 + threadIdx.x;      // over B*W*H
    if (idx >= B_*W_*H_) return;
    int h = idx % H_; int bw = idx / H_; int b = bw / W_;
    int c = tokc[bw]; int cc = min(c, 4);
    double s = 0.0;
    for (int k = 0; k < cc; k++){
        int l = tok[bw*4 + k];
        s += (double)hs[((size_t)(b*L_ + l))*H_ + h];
    }
    float denom = (float)max(c, 1);
    wemb[idx] = (float)(s / (double)denom);
}

// ---------------- entity positions: literal stable scan (early-exits at c==E_) ----------------
__global__ void k_entpos(const int* __restrict__ ent_mask, int* __restrict__ ent_pos){
    int b = blockIdx.x;
    if (threadIdx.x != 0) return;
    int c = 0;
    for (int l = 0; l < L_ && c < E_; l++) if (ent_mask[b*L_ + l] == 1) ent_pos[b*E_ + c++] = l;
    for (int l = 0; l < L_ && c < E_; l++) if (ent_mask[b*L_ + l] != 1) ent_pos[b*E_ + c++] = l;
}

// ---------------- entity MLP (fp64 accumulate) ----------------
__global__ void k_ent_mlp(const float* __restrict__ hs, const int* __restrict__ ent_pos,
                          const float* __restrict__ w1, const float* __restrict__ b1,
                          const float* __restrict__ w2, const float* __restrict__ b2,
                          float* __restrict__ ent_vec){
    __shared__ float x[H_];
    __shared__ float hid[DFF_];
    int be = blockIdx.x; int b = be / E_;
    int tid = threadIdx.x;
    int pos = ent_pos[be];
    const float* xp = hs + ((size_t)b*L_ + pos)*H_;
    for (int j = tid; j < H_; j += 256) x[j] = xp[j];
    __syncthreads();
    for (int d = tid; d < DFF_; d += 256){
        double acc = (double)b1[d];
        for (int h = 0; h < H_; h++) acc += (double)x[h]*(double)w1[(size_t)h*DFF_ + d];
        hid[d] = (float)(acc > 0.0 ? acc : 0.01*acc);
    }
    __syncthreads();
    for (int j = tid; j < H_; j += 256){
        double acc = (double)b2[j];
        for (int d = 0; d < DFF_; d++) acc += (double)hid[d]*(double)w2[(size_t)d*H_ + j];
        ent_vec[(size_t)be*H_ + j] = (float)acc;
    }
}

// ---------------- M[b] = span_w2 @ ent_vec[b]^T ----------------
__global__ void k_M(const float* __restrict__ span_w2, const float* __restrict__ ent_vec,
                    float* __restrict__ M){
    int blk = blockIdx.x; int b = blk/32; int dbase = (blk%32)*16;
    int tid = threadIdx.x; int d = dbase + (tid>>4); int e = tid&15;
    const float* ev = ent_vec + ((size_t)b*E_ + e)*H_;
    double acc = 0.0;
    for (int h = 0; h < H_; h++) acc += (double)span_w2[(size_t)d*H_ + h]*(double)ev[h];
    M[((size_t)b*DFF_ + d)*E_ + e] = (float)acc;
}

__global__ void k_c(const float* __restrict__ span_b2, const float* __restrict__ ent_vec,
                    float* __restrict__ cvec){
    int i = blockIdx.x*blockDim.x + threadIdx.x;
    if (i >= B_*E_) return;
    const float* ev = ent_vec + (size_t)i*H_;
    double acc = 0.0;
    for (int h = 0; h < H_; h++) acc += (double)span_b2[h]*(double)ev[h];
    cvec[i] = (float)acc;
}

// ---------------- P/Q projection, 2 batches per pass ----------------
__global__ void k_pq(const float* __restrict__ wemb, const float* __restrict__ w1,
                     float* __restrict__ PQ, int b0){
    int idx = blockIdx.x*256 + threadIdx.x;      // over 2*W_*1024
    if (idx >= 2*W_*1024) return;
    int col = idx & 1023; int row = idx >> 10;   // row in [0,1008)
    int b = b0 + row / W_; int r = row % W_;
    const float* a = wemb + ((size_t)(b*W_ + r))*H_;
    const float* bp = (col < DFF_) ? (w1 + col) : (w1 + (size_t)H_*DFF_ + (col - DFF_));
    double acc = 0.0;
    for (int k = 0; k < H_; k++) acc += (double)a[k]*(double)bp[(size_t)k*DFF_];
    PQ[(size_t)row*1024 + col] = (float)acc;
}

// ---------------- logits: one block (64 thr) per (bl, span) ----------------
__global__ void k_logits(const float* __restrict__ PQ, const float* __restrict__ Mmat,
                         const float* __restrict__ cvec, const float* __restrict__ span_b1,
                         const int* __restrict__ starts, const int* __restrict__ ends,
                         float* __restrict__ logits, float* __restrict__ outL, int b0){
    __shared__ float hid[DFF_];
    __shared__ double red[64];
    int blk = blockIdx.x;
    int bl = blk / N_; int n = blk - bl*N_;
    int b = b0 + bl;
    int tid = threadIdx.x;
    int s = starts[n], e = ends[n];
    const float* P = PQ + ((size_t)(bl*W_ + s))*1024;
    const float* Q = PQ + ((size_t)(bl*W_ + e))*1024 + DFF_;
    for (int d = tid; d < DFF_; d += 64){
        float h = P[d] + Q[d] + span_b1[d];
        hid[d] = h > 0.f ? h : 0.01f*h;
    }
    __syncthreads();
    int ee = tid & 15; int g = tid >> 4;
    const float* M = Mmat + (size_t)b*DFF_*E_;
    double acc = 0.0;
    for (int d = g*128; d < g*128 + 128; d++) acc += (double)hid[d]*(double)M[(size_t)d*E_ + ee];
    red[tid] = acc; __syncthreads();
    if (tid < E_){
        double t = red[tid] + red[16+tid] + red[32+tid] + red[48+tid];
        float lg = (float)(t + (double)cvec[b*E_ + tid]);
        size_t oi = ((size_t)b*N_ + n)*E_ + tid;
        logits[oi] = lg;
        outL[oi] = lg;
    }
}

// ---------------- per-span best candidate (exact greedy-equivalence reduction) ----------------
// Among a span's 16 candidates only the highest-priority one can ever be taken;
// the rest are provably rejected and never mutate coverage.
__global__ void k_spanbest(const float* __restrict__ logits, u64* __restrict__ candS){
    int idx = blockIdx.x*256 + threadIdx.x;      // over B_*N_
    if (idx >= B_*N_) return;
    int b = idx / N_; int n = idx - b*N_;
    const float* lg = logits + (size_t)b*NE_ + (size_t)n*16;
    u64 best = ~0ull;
    for (int e = 0; e < 16; e++){
        float prob = 1.0f/(1.0f + expf(-lg[e]));   // same fp32 sigmoid as validated R6
        if (prob > 0.5f){
            u32 key24 = (~__float_as_uint(prob)) & 0xFFFFFFu;  // prob in (0.5,1]: 24 significant bits, ascending = prob desc
            u64 pk = ((u64)key24 << 24) | (u64)(u32)(n*16 + e);
            best = best < pk ? best : pk;
        }
    }
    candS[idx] = best;
}

// ---------------- stable compaction of valid span-best candidates (span order) ----------------
__global__ void k_compact2(const u64* __restrict__ candS, u64* __restrict__ candA,
                           int* __restrict__ cnt){
    __shared__ u32 wt[4];
    __shared__ u32 wpre[5];
    __shared__ u32 sbase;
    int b = blockIdx.x; int tid = threadIdx.x;   // 256 threads
    int lane = tid&63, wave = tid>>6;
    if (tid == 0) sbase = 0;
    __syncthreads();
    for (int base = 0; base < N_; base += 256){
        int nidx = base + tid;
        u64 v = (nidx < N_) ? candS[(size_t)b*N_ + nidx] : ~0ull;
        bool f = (v != ~0ull);
        u64 bal = __ballot(f);
        if (lane == 0) wt[wave] = (u32)__popcll(bal);
        __syncthreads();
        if (tid == 0){ u32 r = 0; for (int w = 0; w < 4; w++){ wpre[w] = r; r += wt[w]; } wpre[4] = r; }
        __syncthreads();
        if (f){
            u32 rank = (u32)__popcll(bal & ((1ull<<lane) - 1ull));
            candA[(size_t)b*MAXC_ + sbase + wpre[wave] + rank] = v;
        }
        __syncthreads();
        if (tid == 0) sbase += wpre[4];
        __syncthreads();
    }
    if (tid == 0) cnt[b] = (int)sbase;
}

// ---------------- stable LSD radix: 6 passes of 4 bits over key24 (bits 24..47), one kernel ----------------
__global__ void k_sort(u64* __restrict__ A, u64* __restrict__ Bb, const int* __restrict__ cnt){
    __shared__ u32 hist[16*256];   // 16 KB
    __shared__ u32 wtot[4];
    __shared__ u32 woff[4];
    int b = blockIdx.x; int t = threadIdx.x;     // 256 threads
    int n = cnt[b];
    u64* buf0 = A  + (size_t)b*MAXC_;
    u64* buf1 = Bb + (size_t)b*MAXC_;
    int chunk = (n + 255) >> 8;
    int lo = t*chunk; int hi = lo + chunk; if (hi > n) hi = n; if (lo > n) lo = n;
    int lane = t & 63, wave = t >> 6;
    for (int p = 0; p < 6; p++){
        u64* ip = (p & 1) ? buf1 : buf0;
        u64* op = (p & 1) ? buf0 : buf1;
        int shift = 24 + 4*p;
        for (int j = t; j < 16*256; j += 256) hist[j] = 0;
        __syncthreads();
        for (int i = lo; i < hi; i++) hist[((int)((ip[i] >> shift) & 15ull))*256 + t]++;
        __syncthreads();
        u32 v[16];
        #pragma unroll
        for (int j = 0; j < 16; j++) v[j] = hist[t*16 + j];
        u32 run = 0;
        #pragma unroll
        for (int j = 0; j < 16; j++){ u32 tmp = v[j]; v[j] = run; run += tmp; }
        u32 inc = run;
        for (int d = 1; d < 64; d <<= 1){ u32 o = __shfl_up(inc, d, 64); if (lane >= d) inc += o; }
        u32 excl = inc - run;
        if (lane == 63) wtot[wave] = inc;
        __syncthreads();
        if (t == 0){ u32 r = 0; for (int w = 0; w < 4; w++){ woff[w] = r; r += wtot[w]; } }
        __syncthreads();
        u32 gbase = woff[wave] + excl;
        #pragma unroll
        for (int j = 0; j < 16; j++) hist[t*16 + j] = gbase + v[j];
        __syncthreads();
        for (int i = lo; i < hi; i++){
            u64 val = ip[i];
            int d = (int)((val >> shift) & 15ull);
            u32 pz = hist[d*256 + t];
            hist[d*256 + t] = pz + 1;
            op[pz] = val;
        }
        __syncthreads();
    }
    // 6 passes: final result lands back in buf0 (candA)
}

// ---------------- greedy NMS decode over span-best candidates ----------------
__global__ void k_decode(const u64* __restrict__ sorted, const int* __restrict__ cnt,
                         const int* __restrict__ starts, const int* __restrict__ ends,
                         float* __restrict__ outSel){
    __shared__ u64 covsh[8];
    int b = blockIdx.x; int lane = threadIdx.x;
    if (lane < 8) covsh[lane] = 0ull;
    __syncthreads();
    int n = cnt[b];
    const u64* sp = sorted + (size_t)b*MAXC_;
    int covcnt = 0;
    for (int base = 0; base < n; base += 64){
        int i = base + lane;
        bool has = i < n;
        u64 v = has ? sp[i] : 0ull;
        int c = (int)(v & 0xFFFFFFull);          // flat candidate index n*16+e
        int nidx = c >> 4;
        int s = 0, e = -1;
        if (has){ s = starts[nidx]; e = ends[nidx]; }
        int w0 = s>>6; int sh0 = s&63; int len = e - s + 1;
        u64 m0 = has ? ((((len>=64)?~0ull:((1ull<<len)-1ull)))<<sh0) : 0ull;
        u64 m1 = (has && sh0+len > 64) ? (((1ull<<len)-1ull)>>(64-sh0)) : 0ull;
        int w1 = (w0+1 < 8) ? w0+1 : 7;
        bool tent = has && ((covsh[w0]&m0)==0ull) && ((covsh[w1]&m1)==0ull);
        u64 bal = __ballot(tent);
        while (bal){
            int j = __builtin_ctzll(bal);
            int js = __shfl(s, j); int je = __shfl(e, j); int jc = __shfl(c, j);
            int jw0 = js>>6, jsh = js&63, jlen = je - js + 1;
            u64 jm0 = (((jlen>=64)?~0ull:((1ull<<jlen)-1ull)))<<jsh;
            u64 jm1 = (jsh+jlen > 64) ? (((1ull<<jlen)-1ull)>>(64-jsh)) : 0ull;
            int jw1 = (jw0+1 < 8) ? jw0+1 : 7;
            u64 o0 = covsh[jw0], o1 = covsh[jw1];
            covcnt += (int)(__popcll(jm0 & ~o0) + ((jw1 != jw0) ? __popcll(jm1 & ~o1) : 0));
            if (lane == 0){
                covsh[jw0] = o0 | jm0;
                if (jw1 != jw0) covsh[jw1] = o1 | jm1;
                outSel[(size_t)BNE_ + (size_t)b*NE_ + (size_t)jc] = 1.0f;
            }
            __syncthreads();
            tent = tent && (lane > j) && ((covsh[w0]&m0)==0ull) && ((covsh[w1]&m1)==0ull);
            bal = __ballot(tent);
        }
        if (covcnt >= W_) break;
    }
}

extern "C" void kernel_launch(void* const* d_in, const int* in_sizes, int n_in,
                              void* d_out, int out_size, void* d_ws, size_t ws_size,
                              hipStream_t stream){
    const float* hs        = (const float*)d_in[0];
    const float* ent_w1    = (const float*)d_in[1];
    const float* ent_b1    = (const float*)d_in[2];
    const float* ent_w2    = (const float*)d_in[3];
    const float* ent_b2    = (const float*)d_in[4];
    const float* span_w1   = (const float*)d_in[5];
    const float* span_b1   = (const float*)d_in[6];
    const float* span_w2   = (const float*)d_in[7];
    const float* span_b2   = (const float*)d_in[8];
    const int*  text_mask  = (const int*)d_in[9];
    const int*  ent_mask   = (const int*)d_in[10];
    const int*  word_index = (const int*)d_in[11];
    float* out = (float*)d_out;                   // fp32 outputs (logits, selected as 0/1)

    // ---- workspace (~20 MB peak; candidate buffers overlay dead wemb) ----
    char* wsbase = (char*)d_ws; size_t off = 0;
    auto alloc = [&](size_t bytes)->void*{ void* p = wsbase + off; off = (off + bytes + 255) & ~(size_t)255; return p; };
    char*  region1 = (char*)alloc((size_t)B_*W_*H_*4);    // 12,386,304 B
    float* wemb   = (float*)region1;                       // phase 1
    u64*   candS  = (u64*)region1;                         // phase 2: 382,848 B
    u64*   candA  = (u64*)(region1 + 393216);              // 393,216 B
    u64*   candB  = (u64*)(region1 + 786432);              // 393,216 B
    int*   tok    = (int*)  alloc((size_t)B_*W_*4*4);
    int*   tokc   = (int*)  alloc((size_t)B_*W_*4);
    float* PQ     = (float*)alloc((size_t)2*W_*1024*4);    // 4,128,768 B (2 batches/pass)
    float* logits = (float*)alloc((size_t)BNE_*4);         // 3,062,784 B
    int*   entpos = (int*)  alloc((size_t)B_*E_*4);
    float* entvec = (float*)alloc((size_t)B_*E_*H_*4);
    float* Mmat   = (float*)alloc((size_t)B_*DFF_*E_*4);
    float* cvec   = (float*)alloc((size_t)B_*E_*4);
    int*   starts = (int*)  alloc((size_t)N_*4);
    int*   ends   = (int*)  alloc((size_t)N_*4);
    int*   cntp   = (int*)  alloc((size_t)B_*4);

    hipMemsetAsync((void*)(out + BNE_), 0, (size_t)BNE_*4, stream);   // selected := 0.0f
    hipMemsetAsync(tokc, 0, (size_t)B_*W_*4, stream);

    k_tables<<<8,64,0,stream>>>(starts, ends);
    k_toklist<<<(B_*L_+255)/256,256,0,stream>>>(text_mask, word_index, tok, tokc);
    k_toksort<<<(B_*W_+255)/256,256,0,stream>>>(tok, tokc);
    k_pool<<<(B_*W_*H_+255)/256,256,0,stream>>>(hs, tok, tokc, wemb);
    k_entpos<<<B_,64,0,stream>>>(ent_mask, entpos);
    k_ent_mlp<<<B_*E_,256,0,stream>>>(hs, entpos, ent_w1, ent_b1, ent_w2, ent_b2, entvec);
    k_M<<<B_*32,256,0,stream>>>(span_w2, entvec, Mmat);
    k_c<<<(B_*E_+63)/64,64,0,stream>>>(span_b2, entvec, cvec);
    for (int b0 = 0; b0 < B_; b0 += 2){
        k_pq<<<(2*W_*1024)/256,256,0,stream>>>(wemb, span_w1, PQ, b0);
        k_logits<<<2*N_,64,0,stream>>>(PQ, Mmat, cvec, span_b1, starts, ends, logits, out, b0);
    }
    // wemb dead from here; region1 hosts candS/candA/candB
    k_spanbest<<<(B_*N_+255)/256,256,0,stream>>>(logits, candS);
    k_compact2<<<B_,256,0,stream>>>(candS, candA, cntp);
    k_sort<<<B_,256,0,stream>>>(candA, candB, cntp);
    k_decode<<<B_,64,0,stream>>>(candA, cntp, starts, ends, out);
}

// Round 8
// 693.151 us; speedup vs baseline: 4.5093x; 2.0259x over previous
//
#include <hip/hip_runtime.h>
#include <hip/hip_bf16.h>
#include <stdint.h>

#define B_ 8
#define L_ 1024
#define H_ 768
#define E_ 16
#define W_ 504
#define DFF_ 512
#define N_ 5982
#define NE_ (N_*E_)    // 95712 candidates per batch
#define BNE_ (B_*NE_)  // 765696
#define MAXC_ 6144     // padded per-batch candidate capacity (>= N_)

typedef unsigned long long u64;
typedef unsigned int u32;

__device__ __forceinline__ int rowstart_of(int s){
    int s0 = W_ - 11; // 493
    if (s <= s0) return 12*s;
    int t = s - s0;
    return 12*s0 + t*11 - (t*(t-1))/2;
}

// ---------------- span tables ----------------
__global__ void k_tables(int* starts, int* ends){
    int s = blockIdx.x*64 + threadIdx.x;
    if (s >= W_) return;
    int rs = rowstart_of(s);
    int cnt = min(12, W_ - s);
    for (int i = 0; i < cnt; i++){ starts[rs+i] = s; ends[rs+i] = s+i; }
}

// ---------------- token lists: parallel build + deterministic per-word sort ----------------
__global__ void k_toklist(const int* __restrict__ tm, const int* __restrict__ wi,
                          int* __restrict__ tok, int* __restrict__ tokc){
    int i = blockIdx.x*256 + threadIdx.x;
    if (i >= B_*L_) return;
    int w = wi[i];
    if (tm[i] == 1 && w >= 0 && w < W_){
        int b = i / L_;
        int bw = b*W_ + w;
        int pos = atomicAdd(&tokc[bw], 1);
        if (pos < 4) tok[bw*4 + pos] = i - b*L_;
    }
}

__global__ void k_toksort(int* __restrict__ tok, const int* __restrict__ tokc){
    int bw = blockIdx.x*256 + threadIdx.x;
    if (bw >= B_*W_) return;
    int c = min(tokc[bw], 4);
    int v[4];
    for (int k = 0; k < c; k++) v[k] = tok[bw*4 + k];
    for (int a = 1; a < c; a++){ int x = v[a]; int j = a-1; while (j >= 0 && v[j] > x){ v[j+1] = v[j]; j--; } v[j+1] = x; }
    for (int k = 0; k < c; k++) tok[bw*4 + k] = v[k];
}

// ---------------- word mean pooling (gather, deterministic) ----------------
__global__ void k_pool(const float* __restrict__ hs,
                       const int* __restrict__ tok, const int* __restrict__ tokc,
                       float* __restrict__ wemb){
    int idx = blockIdx.x*256 + threadIdx.x;      // over B*W*H
    if (idx >= B_*W_*H_) return;
    int h = idx % H_; int bw = idx / H_; int b = bw / W_;
    int c = tokc[bw]; int cc = min(c, 4);
    double s = 0.0;
    for (int k = 0; k < cc; k++){
        int l = tok[bw*4 + k];
        s += (double)hs[((size_t)(b*L_ + l))*H_ + h];
    }
    float denom = (float)max(c, 1);
    wemb[idx] = (float)(s / (double)denom);
}

// ---------------- entity positions: literal stable scan ----------------
__global__ void k_entpos(const int* __restrict__ ent_mask, int* __restrict__ ent_pos){
    int b = blockIdx.x;
    if (threadIdx.x != 0) return;
    int c = 0;
    for (int l = 0; l < L_ && c < E_; l++) if (ent_mask[b*L_ + l] == 1) ent_pos[b*E_ + c++] = l;
    for (int l = 0; l < L_ && c < E_; l++) if (ent_mask[b*L_ + l] != 1) ent_pos[b*E_ + c++] = l;
}

// ---------------- entity MLP layer 1: hidg[be,d] = leaky(x[be]·w1[:,d] + b1[d]) ----------------
__global__ void k_ent1(const float* __restrict__ hs, const int* __restrict__ ent_pos,
                       const float* __restrict__ w1, const float* __restrict__ b1,
                       float* __restrict__ hidg){
    __shared__ float x[H_];
    int blk = blockIdx.x;            // 256 blocks: be*2 + half
    int be = blk >> 1; int half = blk & 1;
    int b = be >> 4;
    int tid = threadIdx.x;
    int pos = ent_pos[be];
    const float* xp = hs + ((size_t)b*L_ + pos)*H_;
    for (int j = tid; j < H_; j += 256) x[j] = xp[j];
    __syncthreads();
    int d = half*256 + tid;
    float a0=0.f,a1=0.f,a2=0.f,a3=0.f;
    const float* wp = w1 + d;
    #pragma unroll 4
    for (int h = 0; h < H_; h += 4){
        a0 += x[h+0]*wp[(size_t)(h+0)*DFF_];
        a1 += x[h+1]*wp[(size_t)(h+1)*DFF_];
        a2 += x[h+2]*wp[(size_t)(h+2)*DFF_];
        a3 += x[h+3]*wp[(size_t)(h+3)*DFF_];
    }
    float acc = ((a0+a1)+(a2+a3)) + b1[d];
    hidg[(size_t)be*DFF_ + d] = acc > 0.f ? acc : 0.01f*acc;
}

// ---------------- entity MLP layer 2: ent_vec[be,j] = hid[be]·w2[:,j] + b2[j] ----------------
__global__ void k_ent2(const float* __restrict__ hidg,
                       const float* __restrict__ w2, const float* __restrict__ b2,
                       float* __restrict__ ent_vec){
    __shared__ float hsd[DFF_];
    int blk = blockIdx.x;            // 384 blocks: be*3 + third
    int be = blk / 3; int third = blk % 3;
    int tid = threadIdx.x;
    const float* hp = hidg + (size_t)be*DFF_;
    for (int j = tid; j < DFF_; j += 256) hsd[j] = hp[j];
    __syncthreads();
    int j = third*256 + tid;
    float a0=0.f,a1=0.f,a2=0.f,a3=0.f;
    const float* wp = w2 + j;
    #pragma unroll 4
    for (int d = 0; d < DFF_; d += 4){
        a0 += hsd[d+0]*wp[(size_t)(d+0)*H_];
        a1 += hsd[d+1]*wp[(size_t)(d+1)*H_];
        a2 += hsd[d+2]*wp[(size_t)(d+2)*H_];
        a3 += hsd[d+3]*wp[(size_t)(d+3)*H_];
    }
    ent_vec[(size_t)be*H_ + j] = ((a0+a1)+(a2+a3)) + b2[j];
}

// ---------------- M[b] = span_w2 @ ent_vec[b]^T (fp64, decode-critical) ----------------
__global__ void k_M(const float* __restrict__ span_w2, const float* __restrict__ ent_vec,
                    float* __restrict__ M){
    int blk = blockIdx.x; int b = blk/32; int dbase = (blk%32)*16;
    int tid = threadIdx.x; int d = dbase + (tid>>4); int e = tid&15;
    const float* ev = ent_vec + ((size_t)b*E_ + e)*H_;
    const float* wr = span_w2 + (size_t)d*H_;
    double p0=0.0, p1=0.0;
    for (int h = 0; h < H_; h += 2){
        p0 += (double)wr[h]*(double)ev[h];
        p1 += (double)wr[h+1]*(double)ev[h+1];
    }
    M[((size_t)b*DFF_ + d)*E_ + e] = (float)(p0+p1);
}

__global__ void k_c(const float* __restrict__ span_b2, const float* __restrict__ ent_vec,
                    float* __restrict__ cvec){
    int i = blockIdx.x*blockDim.x + threadIdx.x;
    if (i >= B_*E_) return;
    const float* ev = ent_vec + (size_t)i*H_;
    double acc = 0.0;
    for (int h = 0; h < H_; h++) acc += (double)span_b2[h]*(double)ev[h];
    cvec[i] = (float)acc;
}

// ---------------- P/Q projection: tiled fp32 GEMM, 64x64 tiles, 2 batches per pass ----------------
//   C[1008 x 1024] = A[1008 x 768] @ Bmat[768 x 1024]
//   cols 0..511: W1[0:768, :], cols 512..1023: W1[768:1536, :]
__global__ void k_pq(const float* __restrict__ wemb, const float* __restrict__ w1,
                     float* __restrict__ PQ, int b0){
    __shared__ float As[16][68];   // [k][row], +4 pad keeps 16B alignment
    __shared__ float Bs[16][68];   // [k][col]
    int bx = blockIdx.x & 15;      // col tile
    int by = blockIdx.x >> 4;      // row tile (0..15)
    int tid = threadIdx.x;
    int tm = tid >> 4, tn = tid & 15;
    const float* A0 = wemb + (size_t)b0*W_*H_;
    int colbase = bx*64;
    const float* Bbase = (colbase < DFF_) ? w1 : (w1 + (size_t)H_*DFF_);
    int bcol0 = (colbase < DFF_) ? colbase : (colbase - DFF_);
    float acc[4][4] = {{0.f}};
    // staging indices
    int ar = tid >> 2, akq = tid & 3;            // A: row, k-quad
    int bkk = tid >> 4, bcq = tid & 15;          // B: k, col-quad
    for (int k0 = 0; k0 < H_; k0 += 16){
        {   // A tile: 64 rows x 16 k, float4 per thread
            int gr = by*64 + ar;
            float4 av;
            if (gr < 1008) av = *(const float4*)(A0 + (size_t)gr*H_ + k0 + akq*4);
            else av = make_float4(0.f,0.f,0.f,0.f);
            As[akq*4+0][ar] = av.x; As[akq*4+1][ar] = av.y;
            As[akq*4+2][ar] = av.z; As[akq*4+3][ar] = av.w;
        }
        {   // B tile: 16 k x 64 cols, float4 per thread
            float4 bv = *(const float4*)(Bbase + (size_t)(k0+bkk)*DFF_ + bcol0 + bcq*4);
            Bs[bkk][bcq*4+0] = bv.x; Bs[bkk][bcq*4+1] = bv.y;
            Bs[bkk][bcq*4+2] = bv.z; Bs[bkk][bcq*4+3] = bv.w;
        }
        __syncthreads();
        #pragma unroll
        for (int kk = 0; kk < 16; kk++){
            float4 a = *(const float4*)&As[kk][tm*4];
            float4 bv = *(const float4*)&Bs[kk][tn*4];
            acc[0][0] += a.x*bv.x; acc[0][1] += a.x*bv.y; acc[0][2] += a.x*bv.z; acc[0][3] += a.x*bv.w;
            acc[1][0] += a.y*bv.x; acc[1][1] += a.y*bv.y; acc[1][2] += a.y*bv.z; acc[1][3] += a.y*bv.w;
            acc[2][0] += a.z*bv.x; acc[2][1] += a.z*bv.y; acc[2][2] += a.z*bv.z; acc[2][3] += a.z*bv.w;
            acc[3][0] += a.w*bv.x; acc[3][1] += a.w*bv.y; acc[3][2] += a.w*bv.z; acc[3][3] += a.w*bv.w;
        }
        __syncthreads();
    }
    #pragma unroll
    for (int r = 0; r < 4; r++){
        int gr = by*64 + tm*4 + r;
        if (gr < 1008){
            float4 ov = make_float4(acc[r][0], acc[r][1], acc[r][2], acc[r][3]);
            *(float4*)(PQ + (size_t)gr*1024 + colbase + tn*4) = ov;
        }
    }
}

// ---------------- logits: one block (256 thr) per (bl, start s); M staged once ----------------
__global__ void k_logits(const float* __restrict__ PQ, const float* __restrict__ Mmat,
                         const float* __restrict__ cvec, const float* __restrict__ span_b1,
                         float* __restrict__ logits, float* __restrict__ outL, int b0){
    __shared__ float Msh[DFF_*E_];   // 32 KB
    __shared__ float Ps[DFF_];
    __shared__ float hid[DFF_];
    __shared__ double red[256];
    __shared__ float csh[E_];
    int blk = blockIdx.x;            // 2*W_ blocks
    int bl = blk / W_; int s = blk - bl*W_;
    int b = b0 + bl;
    int tid = threadIdx.x;
    for (int i = tid; i < DFF_*E_; i += 256) Msh[i] = Mmat[(size_t)b*DFF_*E_ + i];
    const float* P = PQ + ((size_t)(bl*W_ + s))*1024;
    for (int d = tid; d < DFF_; d += 256) Ps[d] = P[d] + span_b1[d];
    if (tid < E_) csh[tid] = cvec[b*E_ + tid];
    __syncthreads();
    int nsp = min(12, W_ - s);
    int nbase = rowstart_of(s);
    for (int i = 0; i < nsp; i++){
        int e = s + i;
        const float* Q = PQ + ((size_t)(bl*W_ + e))*1024 + DFF_;
        for (int d = tid; d < DFF_; d += 256){
            float h = Ps[d] + Q[d];
            hid[d] = h > 0.f ? h : 0.01f*h;
        }
        __syncthreads();
        {
            int ee = tid & 15; int g = tid >> 4;   // 16 groups x 32 d
            double acc = 0.0;
            int d0 = g*32;
            for (int d = d0; d < d0+32; d++) acc += (double)hid[d]*(double)Msh[d*E_ + ee];
            red[tid] = acc;
        }
        __syncthreads();
        if (tid < E_){
            double t = 0.0;
            for (int g = 0; g < 16; g++) t += red[g*16 + tid];
            float lg = (float)(t + (double)csh[tid]);
            size_t oi = ((size_t)b*N_ + nbase + i)*E_ + tid;
            logits[oi] = lg;
            outL[oi] = lg;
        }
        __syncthreads();
    }
}

// ---------------- per-span best candidate (exact greedy-equivalence reduction) ----------------
__global__ void k_spanbest(const float* __restrict__ logits, u64* __restrict__ candS){
    int idx = blockIdx.x*256 + threadIdx.x;      // over B_*N_
    if (idx >= B_*N_) return;
    int b = idx / N_; int n = idx - b*N_;
    const float* lg = logits + (size_t)b*NE_ + (size_t)n*16;
    u64 best = ~0ull;
    for (int e = 0; e < 16; e++){
        float prob = 1.0f/(1.0f + expf(-lg[e]));
        if (prob > 0.5f){
            u32 key24 = (~__float_as_uint(prob)) & 0xFFFFFFu;
            u64 pk = ((u64)key24 << 24) | (u64)(u32)(n*16 + e);
            best = best < pk ? best : pk;
        }
    }
    candS[idx] = best;
}

// ---------------- stable compaction (span order) ----------------
__global__ void k_compact2(const u64* __restrict__ candS, u64* __restrict__ candA,
                           int* __restrict__ cnt){
    __shared__ u32 wt[4];
    __shared__ u32 wpre[5];
    __shared__ u32 sbase;
    int b = blockIdx.x; int tid = threadIdx.x;
    int lane = tid&63, wave = tid>>6;
    if (tid == 0) sbase = 0;
    __syncthreads();
    for (int base = 0; base < N_; base += 256){
        int nidx = base + tid;
        u64 v = (nidx < N_) ? candS[(size_t)b*N_ + nidx] : ~0ull;
        bool f = (v != ~0ull);
        u64 bal = __ballot(f);
        if (lane == 0) wt[wave] = (u32)__popcll(bal);
        __syncthreads();
        if (tid == 0){ u32 r = 0; for (int w = 0; w < 4; w++){ wpre[w] = r; r += wt[w]; } wpre[4] = r; }
        __syncthreads();
        if (f){
            u32 rank = (u32)__popcll(bal & ((1ull<<lane) - 1ull));
            candA[(size_t)b*MAXC_ + sbase + wpre[wave] + rank] = v;
        }
        __syncthreads();
        if (tid == 0) sbase += wpre[4];
        __syncthreads();
    }
    if (tid == 0) cnt[b] = (int)sbase;
}

// ---------------- stable LSD radix: 6 x 4-bit over key24 (bits 24..47), single kernel ----------------
__global__ void k_sort(u64* __restrict__ A, u64* __restrict__ Bb, const int* __restrict__ cnt){
    __shared__ u32 hist[16*256];
    __shared__ u32 wtot[4];
    __shared__ u32 woff[4];
    int b = blockIdx.x; int t = threadIdx.x;
    int n = cnt[b];
    u64* buf0 = A  + (size_t)b*MAXC_;
    u64* buf1 = Bb + (size_t)b*MAXC_;
    int chunk = (n + 255) >> 8;
    int lo = t*chunk; int hi = lo + chunk; if (hi > n) hi = n; if (lo > n) lo = n;
    int lane = t & 63, wave = t >> 6;
    for (int p = 0; p < 6; p++){
        u64* ip = (p & 1) ? buf1 : buf0;
        u64* op = (p & 1) ? buf0 : buf1;
        int shift = 24 + 4*p;
        for (int j = t; j < 16*256; j += 256) hist[j] = 0;
        __syncthreads();
        for (int i = lo; i < hi; i++) hist[((int)((ip[i] >> shift) & 15ull))*256 + t]++;
        __syncthreads();
        u32 v[16];
        #pragma unroll
        for (int j = 0; j < 16; j++) v[j] = hist[t*16 + j];
        u32 run = 0;
        #pragma unroll
        for (int j = 0; j < 16; j++){ u32 tmp = v[j]; v[j] = run; run += tmp; }
        u32 inc = run;
        for (int d = 1; d < 64; d <<= 1){ u32 o = __shfl_up(inc, d, 64); if (lane >= d) inc += o; }
        u32 excl = inc - run;
        if (lane == 63) wtot[wave] = inc;
        __syncthreads();
        if (t == 0){ u32 r = 0; for (int w = 0; w < 4; w++){ woff[w] = r; r += wtot[w]; } }
        __syncthreads();
        u32 gbase = woff[wave] + excl;
        #pragma unroll
        for (int j = 0; j < 16; j++) hist[t*16 + j] = gbase + v[j];
        __syncthreads();
        for (int i = lo; i < hi; i++){
            u64 val = ip[i];
            int d = (int)((val >> shift) & 15ull);
            u32 pz = hist[d*256 + t];
            hist[d*256 + t] = pz + 1;
            op[pz] = val;
        }
        __syncthreads();
    }
}

// ---------------- greedy NMS decode over span-best candidates ----------------
__global__ void k_decode(const u64* __restrict__ sorted, const int* __restrict__ cnt,
                         const int* __restrict__ starts, const int* __restrict__ ends,
                         float* __restrict__ outSel){
    __shared__ u64 covsh[8];
    int b = blockIdx.x; int lane = threadIdx.x;
    if (lane < 8) covsh[lane] = 0ull;
    __syncthreads();
    int n = cnt[b];
    const u64* sp = sorted + (size_t)b*MAXC_;
    int covcnt = 0;
    for (int base = 0; base < n; base += 64){
        int i = base + lane;
        bool has = i < n;
        u64 v = has ? sp[i] : 0ull;
        int c = (int)(v & 0xFFFFFFull);
        int nidx = c >> 4;
        int s = 0, e = -1;
        if (has){ s = starts[nidx]; e = ends[nidx]; }
        int w0 = s>>6; int sh0 = s&63; int len = e - s + 1;
        u64 m0 = has ? ((((len>=64)?~0ull:((1ull<<len)-1ull)))<<sh0) : 0ull;
        u64 m1 = (has && sh0+len > 64) ? (((1ull<<len)-1ull)>>(64-sh0)) : 0ull;
        int w1 = (w0+1 < 8) ? w0+1 : 7;
        bool tent = has && ((covsh[w0]&m0)==0ull) && ((covsh[w1]&m1)==0ull);
        u64 bal = __ballot(tent);
        while (bal){
            int j = __builtin_ctzll(bal);
            int js = __shfl(s, j); int je = __shfl(e, j); int jc = __shfl(c, j);
            int jw0 = js>>6, jsh = js&63, jlen = je - js + 1;
            u64 jm0 = (((jlen>=64)?~0ull:((1ull<<jlen)-1ull)))<<jsh;
            u64 jm1 = (jsh+jlen > 64) ? (((1ull<<jlen)-1ull)>>(64-jsh)) : 0ull;
            int jw1 = (jw0+1 < 8) ? jw0+1 : 7;
            u64 o0 = covsh[jw0], o1 = covsh[jw1];
            covcnt += (int)(__popcll(jm0 & ~o0) + ((jw1 != jw0) ? __popcll(jm1 & ~o1) : 0));
            if (lane == 0){
                covsh[jw0] = o0 | jm0;
                if (jw1 != jw0) covsh[jw1] = o1 | jm1;
                outSel[(size_t)BNE_ + (size_t)b*NE_ + (size_t)jc] = 1.0f;
            }
            __syncthreads();
            tent = tent && (lane > j) && ((covsh[w0]&m0)==0ull) && ((covsh[w1]&m1)==0ull);
            bal = __ballot(tent);
        }
        if (covcnt >= W_) break;
    }
}

extern "C" void kernel_launch(void* const* d_in, const int* in_sizes, int n_in,
                              void* d_out, int out_size, void* d_ws, size_t ws_size,
                              hipStream_t stream){
    const float* hs        = (const float*)d_in[0];
    const float* ent_w1    = (const float*)d_in[1];
    const float* ent_b1    = (const float*)d_in[2];
    const float* ent_w2    = (const float*)d_in[3];
    const float* ent_b2    = (const float*)d_in[4];
    const float* span_w1   = (const float*)d_in[5];
    const float* span_b1   = (const float*)d_in[6];
    const float* span_w2   = (const float*)d_in[7];
    const float* span_b2   = (const float*)d_in[8];
    const int*  text_mask  = (const int*)d_in[9];
    const int*  ent_mask   = (const int*)d_in[10];
    const int*  word_index = (const int*)d_in[11];
    float* out = (float*)d_out;

    // ---- workspace (~20.8 MB peak; candidate buffers overlay dead wemb) ----
    char* wsbase = (char*)d_ws; size_t off = 0;
    auto alloc = [&](size_t bytes)->void*{ void* p = wsbase + off; off = (off + bytes + 255) & ~(size_t)255; return p; };
    char*  region1 = (char*)alloc((size_t)B_*W_*H_*4);    // 12,386,304 B
    float* wemb   = (float*)region1;                       // phase 1
    u64*   candS  = (u64*)region1;                         // phase 2: 382,848 B
    u64*   candA  = (u64*)(region1 + 393216);              // 393,216 B
    u64*   candB  = (u64*)(region1 + 786432);              // 393,216 B
    int*   tok    = (int*)  alloc((size_t)B_*W_*4*4);
    int*   tokc   = (int*)  alloc((size_t)B_*W_*4);
    float* PQ     = (float*)alloc((size_t)2*W_*1024*4);    // 4,128,768 B (2 batches/pass)
    float* logits = (float*)alloc((size_t)BNE_*4);         // 3,062,784 B
    int*   entpos = (int*)  alloc((size_t)B_*E_*4);
    float* hidg   = (float*)alloc((size_t)B_*E_*DFF_*4);   // 262,144 B
    float* entvec = (float*)alloc((size_t)B_*E_*H_*4);
    float* Mmat   = (float*)alloc((size_t)B_*DFF_*E_*4);
    float* cvec   = (float*)alloc((size_t)B_*E_*4);
    int*   starts = (int*)  alloc((size_t)N_*4);
    int*   ends   = (int*)  alloc((size_t)N_*4);
    int*   cntp   = (int*)  alloc((size_t)B_*4);

    hipMemsetAsync((void*)(out + BNE_), 0, (size_t)BNE_*4, stream);   // selected := 0.0f
    hipMemsetAsync(tokc, 0, (size_t)B_*W_*4, stream);

    k_tables<<<8,64,0,stream>>>(starts, ends);
    k_toklist<<<(B_*L_+255)/256,256,0,stream>>>(text_mask, word_index, tok, tokc);
    k_toksort<<<(B_*W_+255)/256,256,0,stream>>>(tok, tokc);
    k_pool<<<(B_*W_*H_+255)/256,256,0,stream>>>(hs, tok, tokc, wemb);
    k_entpos<<<B_,64,0,stream>>>(ent_mask, entpos);
    k_ent1<<<B_*E_*2,256,0,stream>>>(hs, entpos, ent_w1, ent_b1, hidg);
    k_ent2<<<B_*E_*3,256,0,stream>>>(hidg, ent_w2, ent_b2, entvec);
    k_M<<<B_*32,256,0,stream>>>(span_w2, entvec, Mmat);
    k_c<<<(B_*E_+63)/64,64,0,stream>>>(span_b2, entvec, cvec);
    for (int b0 = 0; b0 < B_; b0 += 2){
        k_pq<<<256,256,0,stream>>>(wemb, span_w1, PQ, b0);
        k_logits<<<2*W_,256,0,stream>>>(PQ, Mmat, cvec, span_b1, logits, out, b0);
    }
    // wemb dead from here; region1 hosts candS/candA/candB
    k_spanbest<<<(B_*N_+255)/256,256,0,stream>>>(logits, candS);
    k_compact2<<<B_,256,0,stream>>>(candS, candA, cntp);
    k_sort<<<B_,256,0,stream>>>(candA, candB, cntp);
    k_decode<<<B_,64,0,stream>>>(candA, cntp, starts, ends, out);
}